// Round 4
// baseline (99.721 us; speedup 1.0000x reference)
//
#include <hip/hip_runtime.h>
#include <stdint.h>

typedef __attribute__((ext_vector_type(8))) short bf16x8;
typedef __attribute__((ext_vector_type(4))) float f32x4;

#define NROWS 4096
#define DDIM  1024
#define NT    64        // 4096/64 panels of 64 rows
#define NBLK2 2080      // NT*(NT+1)/2 triangular 64x64 tiles
#define COS_EPS 1e-8f

__device__ __forceinline__ ushort f2bf(float x) {
  union { float f; uint32_t u; } v; v.f = x;
  uint32_t r = (v.u + 0x7FFF + ((v.u >> 16) & 1)) >> 16;  // RNE
  return (ushort)r;
}

// ---------------- prep: sq, 1/norm, bf16 copy ----------------
extern "C" __global__ void __launch_bounds__(256) prep_kernel(
    const float* __restrict__ F, ushort* __restrict__ Fb,
    float* __restrict__ sq, float* __restrict__ rn) {
  const int row  = blockIdx.x * 4 + (threadIdx.x >> 6);
  const int lane = threadIdx.x & 63;
  const float4* src = (const float4*)(F + (size_t)row * DDIM);
  ushort4* dst = (ushort4*)(Fb + (size_t)row * DDIM);
  float s = 0.f;
#pragma unroll
  for (int it = 0; it < 4; ++it) {
    float4 v = src[it * 64 + lane];
    s += v.x * v.x + v.y * v.y + v.z * v.z + v.w * v.w;
    ushort4 b;
    b.x = f2bf(v.x); b.y = f2bf(v.y); b.z = f2bf(v.z); b.w = f2bf(v.w);
    dst[it * 64 + lane] = b;
  }
#pragma unroll
  for (int off = 32; off; off >>= 1) s += __shfl_down(s, off);
  if (lane == 0) {
    sq[row] = s;
    rn[row] = 1.0f / fmaxf(sqrtf(s), COS_EPS);
  }
}

// ---------------- gram tile (64x64 per wave, L2-direct, no LDS) ----------------
// One 64-thread block per triangular tile. Fragments loaded straight from
// global (L2-resident 8 MB), register double-buffered, fully unrolled K.
extern "C" __global__ void __launch_bounds__(64) gram_kernel(
    const ushort* __restrict__ Fb, const float* __restrict__ sq,
    const float* __restrict__ rn, const int* __restrict__ y,
    float* __restrict__ partials) {
  // ---- XCD-chunked bijective remap (2080 = 8*260) + 8x8 supertile decode ----
  int s = (int)(blockIdx.x & 7) * 260 + (int)(blockIdx.x >> 3);
  int ti, tj;
  {
    int rem = s, SI = 0, SJ = 0;
    bool fnd = false;
    for (SI = 0; SI < 8 && !fnd; ++SI) {
      for (SJ = SI; SJ < 8; ++SJ) {
        int cnt = (SI == SJ) ? 36 : 64;
        if (rem < cnt) { fnd = true; break; }
        rem -= cnt;
      }
      if (fnd) break;
    }
    int li, lj;
    if (SI == SJ) {           // triangular 8x8 super: 36 tiles
      li = 0;
      while (rem >= 8 - li) { rem -= 8 - li; ++li; }
      lj = li + rem;
    } else {                  // full 8x8 super: 64 tiles
      li = rem >> 3; lj = rem & 7;
    }
    ti = SI * 8 + li; tj = SJ * 8 + lj;
  }

  const int lane = threadIdx.x & 63;
  const int fr = lane & 15;        // fragment row
  const int fg = lane >> 4;        // k-group
  const int rowI = ti * 64, colJ = tj * 64;

  // per-lane fragment base pointers (k-offsets fold into imm offset: kt*64B<=1984)
  const ushort* pa[4];
  const ushort* pb[4];
#pragma unroll
  for (int m = 0; m < 4; ++m) {
    pa[m] = Fb + (size_t)(rowI + m * 16 + fr) * DDIM + fg * 8;
    pb[m] = Fb + (size_t)(colJ + m * 16 + fr) * DDIM + fg * 8;
  }

  f32x4 acc[4][4] = {};
  bf16x8 aA[4], bA[4], aB[4], bB[4];

#define LDF(da, db, kk) do {                                                \
    _Pragma("unroll")                                                       \
    for (int _m = 0; _m < 4; ++_m) {                                        \
      da[_m] = *(const bf16x8*)(pa[_m] + (kk) * 32);                        \
      db[_m] = *(const bf16x8*)(pb[_m] + (kk) * 32);                        \
    }                                                                       \
  } while (0)

#define MM(av, bv) do {                                                     \
    _Pragma("unroll")                                                       \
    for (int _m = 0; _m < 4; ++_m)                                          \
      _Pragma("unroll")                                                     \
      for (int _n = 0; _n < 4; ++_n)                                        \
        acc[_m][_n] = __builtin_amdgcn_mfma_f32_16x16x32_bf16(              \
            av[_m], bv[_n], acc[_m][_n], 0, 0, 0);                          \
  } while (0)

  LDF(aA, bA, 0);
#pragma unroll
  for (int kp = 0; kp < 16; ++kp) {
    if (2 * kp + 1 < 32) LDF(aB, bB, 2 * kp + 1);
    MM(aA, bA);
    if (2 * kp + 2 < 32) LDF(aA, bA, 2 * kp + 2);
    MM(aB, bB);
  }

#undef LDF
#undef MM

  // ---------- epilogue ----------
  const float w = (ti == tj) ? 1.0f : 2.0f;

  float sqr[16], rnr[16];
  int   yr[16];
#pragma unroll
  for (int m = 0; m < 4; ++m)
#pragma unroll
    for (int v = 0; v < 4; ++v) {
      int gi = rowI + m * 16 + fg * 4 + v;
      sqr[m * 4 + v] = sq[gi];
      rnr[m * 4 + v] = rn[gi];
      yr[m * 4 + v]  = y[gi];
    }
  float sqc[4], rnc[4];
  int   yc[4];
#pragma unroll
  for (int n = 0; n < 4; ++n) {
    int gj = colJ + n * 16 + fr;
    sqc[n] = sq[gj];
    rnc[n] = rn[gj];
    yc[n]  = y[gj];
  }

  float lsum = 0.f;
#pragma unroll
  for (int m = 0; m < 4; ++m)
#pragma unroll
    for (int n = 0; n < 4; ++n)
#pragma unroll
      for (int v = 0; v < 4; ++v) {
        float g  = acc[m][n][v];
        float d2 = sqr[m * 4 + v] + sqc[n] - 2.0f * g;
        float dist = d2 > 0.f ? sqrtf(d2) : 0.f;
        float sim  = g * rnr[m * 4 + v] * rnc[n];
        float sgn  = (yr[m * 4 + v] == yc[n]) ? 1.0f : -1.0f;
        lsum += sgn * (dist - sim);
      }
  lsum *= w;

#pragma unroll
  for (int off = 32; off; off >>= 1) lsum += __shfl_down(lsum, off);
  if (lane == 0) partials[blockIdx.x] = lsum;
}

// ---------------- deterministic final reduce ----------------
extern "C" __global__ void __launch_bounds__(256) reduce_kernel(
    const float* __restrict__ partials, float* __restrict__ out) {
  float s = 0.f;
  for (int i = threadIdx.x; i < NBLK2; i += 256) s += partials[i];
#pragma unroll
  for (int off = 32; off; off >>= 1) s += __shfl_down(s, off);
  __shared__ float ws[4];
  if ((threadIdx.x & 63) == 0) ws[threadIdx.x >> 6] = s;
  __syncthreads();
  if (threadIdx.x == 0) out[0] = ws[0] + ws[1] + ws[2] + ws[3];
}

extern "C" void kernel_launch(void* const* d_in, const int* in_sizes, int n_in,
                              void* d_out, int out_size, void* d_ws, size_t ws_size,
                              hipStream_t stream) {
  const float* F = (const float*)d_in[0];
  const int*   y = (const int*)d_in[1];
  float* out = (float*)d_out;

  ushort* Fb = (ushort*)d_ws;                                 // 8 MB bf16
  float*  sq = (float*)((char*)d_ws + (size_t)NROWS * DDIM * 2);
  float*  rn = sq + NROWS;
  float*  partials = rn + NROWS;

  prep_kernel<<<NROWS / 4, 256, 0, stream>>>(F, Fb, sq, rn);
  gram_kernel<<<NBLK2, 64, 0, stream>>>(Fb, sq, rn, y, partials);
  reduce_kernel<<<1, 256, 0, stream>>>(partials, out);
}

// Round 5
// 59.132 us; speedup vs baseline: 1.6864x; 1.6864x over previous
//
#include <hip/hip_runtime.h>
#include <stdint.h>

typedef __attribute__((ext_vector_type(8))) short bf16x8;
typedef __attribute__((ext_vector_type(4))) float f32x4;

#define NROWS 4096
#define DDIM  1024
#define NKT   32      // K-tiles of BK=32
#define GBLK  256     // 16x16 grid of 256x256 output tiles (full gram)
#define COS_EPS 1e-8f

__device__ __forceinline__ ushort f2bf(float x) {
  union { float f; uint32_t u; } v; v.f = x;
  uint32_t r = (v.u + 0x7FFF + ((v.u >> 16) & 1)) >> 16;  // RNE
  return (ushort)r;
}

__device__ __forceinline__ void gload16(const ushort* g, ushort* l) {
  __builtin_amdgcn_global_load_lds(
      (const __attribute__((address_space(1))) uint32_t*)g,
      (__attribute__((address_space(3))) uint32_t*)l, 16, 0, 0);
}

// ---------------- prep: sq, 1/norm, bf16 copy ----------------
extern "C" __global__ void __launch_bounds__(256) prep_kernel(
    const float* __restrict__ F, ushort* __restrict__ Fb,
    float* __restrict__ sq, float* __restrict__ rn) {
  const int row  = blockIdx.x * 4 + (threadIdx.x >> 6);
  const int lane = threadIdx.x & 63;
  const float4* src = (const float4*)(F + (size_t)row * DDIM);
  ushort4* dst = (ushort4*)(Fb + (size_t)row * DDIM);
  float s = 0.f;
#pragma unroll
  for (int it = 0; it < 4; ++it) {
    float4 v = src[it * 64 + lane];
    s += v.x * v.x + v.y * v.y + v.z * v.z + v.w * v.w;
    ushort4 b;
    b.x = f2bf(v.x); b.y = f2bf(v.y); b.z = f2bf(v.z); b.w = f2bf(v.w);
    dst[it * 64 + lane] = b;
  }
#pragma unroll
  for (int off = 32; off; off >>= 1) s += __shfl_down(s, off);
  if (lane == 0) {
    sq[row] = s;
    rn[row] = 1.0f / fmaxf(sqrtf(s), COS_EPS);
  }
}

// ---------------- fused gram (256x256 tile, deep pipeline) + epilogue ------
// 8 waves (2Mx4N), per-wave 128x64 out. BK=32, 4-buffer LDS ring, stage 3
// K-tiles ahead, counted vmcnt(8) at K-tile boundaries (never 0 mid-loop).
// LDS holds a per-16-row-group column-major permutation of each K-tile
// (written linearly by global_load_lds from a pre-permuted global source),
// so every ds_read_b128 is one contiguous 1KB wave read (conflict-free).
extern "C" __global__ void __launch_bounds__(512, 2) gram_kernel(
    const ushort* __restrict__ Fb, const float* __restrict__ sq,
    const float* __restrict__ rn, const int* __restrict__ y,
    float* __restrict__ partials) {
  __shared__ __align__(16) ushort As[4][8192];   // 4 bufs x 16KB (256x32 bf16)
  __shared__ __align__(16) ushort Bs[4][8192];

  // XCD-aware remap (256 % 8 == 0 -> simple bijection)
  const int wg = (int)(blockIdx.x & 7) * 32 + (int)(blockIdx.x >> 3);
  const int bi = wg >> 4, bj = wg & 15;

  const int tid  = threadIdx.x;
  const int lane = tid & 63;
  const int wid  = tid >> 6;
  const int wr   = wid >> 2;     // 0..1 : 128-row half
  const int wc   = wid & 3;      // 0..3 : 64-col group
  const int fr   = lane & 15, fg = lane >> 4;

  // ---- staging source (pre-permuted global address; LDS written linearly)
  // LDS slot s = round*512 + tid (16B units) holds global
  // (row = (s>>6)*16 + (s&15), kchunk = (s>>4)&3) of the K-tile.
  const int grow = ((tid >> 6) << 4) + (tid & 15);    // 0..127 (round0)
  const int gchk = ((tid >> 4) & 3) * 8;              // bf16 col within K-tile
  const ushort* gA = Fb + (size_t)(bi * 256 + grow) * DDIM + gchk;
  const ushort* gB = Fb + (size_t)(bj * 256 + grow) * DDIM + gchk;
  ushort* ldsA = &As[0][0] + tid * 8;
  ushort* ldsB = &Bs[0][0] + tid * 8;

  f32x4 acc[8][4] = {};

#define STAGE_A(kt3) do {                                                   \
    const ushort* _s = gA + (kt3) * 32;                                     \
    ushort* _d = ldsA + ((kt3) & 3) * 8192;                                 \
    gload16(_s, _d);                                                        \
    gload16(_s + (size_t)128 * DDIM, _d + 4096);                            \
  } while (0)
#define STAGE_B(kt3) do {                                                   \
    const ushort* _s = gB + (kt3) * 32;                                     \
    ushort* _d = ldsB + ((kt3) & 3) * 8192;                                 \
    gload16(_s, _d);                                                        \
    gload16(_s + (size_t)128 * DDIM, _d + 4096);                            \
  } while (0)

  // prologue: K-tiles 0,1,2 in flight; wait for kt0 (8 left outstanding)
  STAGE_A(0); STAGE_B(0);
  STAGE_A(1); STAGE_B(1);
  STAGE_A(2); STAGE_B(2);
  asm volatile("s_waitcnt vmcnt(8)" ::: "memory");
  __builtin_amdgcn_s_barrier();

  bf16x8 Ar[4], Br[4];
#pragma unroll 1
  for (int kt = 0; kt < NKT; ++kt) {
    const ushort* ap = &As[0][0] + (kt & 3) * 8192 + wr * 4096 + lane * 8;
    const ushort* bp = &Bs[0][0] + (kt & 3) * 8192 + wc * 2048 + lane * 8;

    // ---- phase 0: read B(all) + A(m0..3) | stage A(kt+3) | 16 MFMA ----
#pragma unroll
    for (int n = 0; n < 4; ++n) Br[n] = *(const bf16x8*)(bp + n * 512);
#pragma unroll
    for (int m = 0; m < 4; ++m) Ar[m] = *(const bf16x8*)(ap + m * 512);
    if (kt + 3 < NKT) STAGE_A(kt + 3);
    __builtin_amdgcn_s_barrier();
    asm volatile("s_waitcnt lgkmcnt(0)" ::: "memory");
    __builtin_amdgcn_sched_barrier(0);
    __builtin_amdgcn_s_setprio(1);
#pragma unroll
    for (int m = 0; m < 4; ++m)
#pragma unroll
      for (int n = 0; n < 4; ++n)
        acc[m][n] = __builtin_amdgcn_mfma_f32_16x16x32_bf16(
            Ar[m], Br[n], acc[m][n], 0, 0, 0);
    __builtin_amdgcn_s_setprio(0);
    __builtin_amdgcn_s_barrier();

    // ---- phase 1: read A(m4..7) | stage B(kt+3) | boundary vmcnt | 16 MFMA
#pragma unroll
    for (int m = 0; m < 4; ++m) Ar[m] = *(const bf16x8*)(ap + (4 + m) * 512);
    if (kt + 3 < NKT) STAGE_B(kt + 3);
    if (kt < NKT - 3)       asm volatile("s_waitcnt vmcnt(8)" ::: "memory");
    else if (kt == NKT - 3) asm volatile("s_waitcnt vmcnt(4)" ::: "memory");
    else if (kt == NKT - 2) asm volatile("s_waitcnt vmcnt(0)" ::: "memory");
    __builtin_amdgcn_s_barrier();
    asm volatile("s_waitcnt lgkmcnt(0)" ::: "memory");
    __builtin_amdgcn_sched_barrier(0);
    __builtin_amdgcn_s_setprio(1);
#pragma unroll
    for (int m = 0; m < 4; ++m)
#pragma unroll
      for (int n = 0; n < 4; ++n)
        acc[4 + m][n] = __builtin_amdgcn_mfma_f32_16x16x32_bf16(
            Ar[m], Br[n], acc[4 + m][n], 0, 0, 0);
    __builtin_amdgcn_s_setprio(0);
    __builtin_amdgcn_s_barrier();
  }

#undef STAGE_A
#undef STAGE_B

  // ---------- epilogue (full gram: every pair once, weight 1) ----------
  const int gi0 = bi * 256 + wr * 128 + fg * 4;
  const int gj0 = bj * 256 + wc * 64 + fr;
  float sqc[4], rnc[4];
  int   yc[4];
#pragma unroll
  for (int n = 0; n < 4; ++n) {
    const int gj = gj0 + n * 16;
    sqc[n] = sq[gj]; rnc[n] = rn[gj]; yc[n] = y[gj];
  }
  float lsum = 0.f;
#pragma unroll
  for (int m = 0; m < 8; ++m) {
#pragma unroll
    for (int v = 0; v < 4; ++v) {
      const int gi = gi0 + m * 16 + v;
      const float sqi = sq[gi], rni = rn[gi];
      const int yi = y[gi];
#pragma unroll
      for (int n = 0; n < 4; ++n) {
        const float g  = acc[m][n][v];
        const float d2 = sqi + sqc[n] - 2.0f * g;
        const float dist = d2 > 0.f ? sqrtf(d2) : 0.f;
        const float sim  = g * rni * rnc[n];
        lsum += (yi == yc[n]) ? (dist - sim) : (sim - dist);
      }
    }
  }
#pragma unroll
  for (int off = 32; off; off >>= 1) lsum += __shfl_down(lsum, off);
  __shared__ float wsum[8];
  if (lane == 0) wsum[wid] = lsum;
  __syncthreads();
  if (tid == 0) {
    float t = 0.f;
#pragma unroll
    for (int i = 0; i < 8; ++i) t += wsum[i];
    partials[blockIdx.x] = t;
  }
}

// ---------------- deterministic final reduce ----------------
extern "C" __global__ void __launch_bounds__(256) reduce_kernel(
    const float* __restrict__ partials, float* __restrict__ out) {
  float s = 0.f;
  for (int i = threadIdx.x; i < GBLK; i += 256) s += partials[i];
#pragma unroll
  for (int off = 32; off; off >>= 1) s += __shfl_down(s, off);
  __shared__ float ws[4];
  if ((threadIdx.x & 63) == 0) ws[threadIdx.x >> 6] = s;
  __syncthreads();
  if (threadIdx.x == 0) out[0] = ws[0] + ws[1] + ws[2] + ws[3];
}

extern "C" void kernel_launch(void* const* d_in, const int* in_sizes, int n_in,
                              void* d_out, int out_size, void* d_ws, size_t ws_size,
                              hipStream_t stream) {
  const float* F = (const float*)d_in[0];
  const int*   y = (const int*)d_in[1];
  float* out = (float*)d_out;

  ushort* Fb = (ushort*)d_ws;                                 // 8 MB bf16
  float*  sq = (float*)((char*)d_ws + (size_t)NROWS * DDIM * 2);
  float*  rn = sq + NROWS;
  float*  partials = rn + NROWS;

  prep_kernel<<<NROWS / 4, 256, 0, stream>>>(F, Fb, sq, rn);
  gram_kernel<<<GBLK, 512, 0, stream>>>(Fb, sq, rn, y, partials);
  reduce_kernel<<<1, 256, 0, stream>>>(partials, out);
}

// Round 6
// 58.638 us; speedup vs baseline: 1.7006x; 1.0084x over previous
//
#include <hip/hip_runtime.h>
#include <stdint.h>

typedef __attribute__((ext_vector_type(8))) short bf16x8;
typedef __attribute__((ext_vector_type(4))) float f32x4;

#define NROWS 4096
#define DDIM  1024
#define NKT   32      // K-tiles of BK=32
#define GBLK  256     // 16x16 grid of 256x256 output tiles (full gram)
#define COS_EPS 1e-8f

__device__ __forceinline__ ushort f2bf(float x) {
  union { float f; uint32_t u; } v; v.f = x;
  uint32_t r = (v.u + 0x7FFF + ((v.u >> 16) & 1)) >> 16;  // RNE
  return (ushort)r;
}

__device__ __forceinline__ void gload16(const ushort* g, ushort* l) {
  __builtin_amdgcn_global_load_lds(
      (const __attribute__((address_space(1))) uint32_t*)g,
      (__attribute__((address_space(3))) uint32_t*)l, 16, 0, 0);
}

// ---------------- prep: sq, 1/norm, bf16 copy ----------------
extern "C" __global__ void __launch_bounds__(256) prep_kernel(
    const float* __restrict__ F, ushort* __restrict__ Fb,
    float* __restrict__ sq, float* __restrict__ rn) {
  const int row  = blockIdx.x * 4 + (threadIdx.x >> 6);
  const int lane = threadIdx.x & 63;
  const float4* src = (const float4*)(F + (size_t)row * DDIM);
  ushort4* dst = (ushort4*)(Fb + (size_t)row * DDIM);
  float s = 0.f;
#pragma unroll
  for (int it = 0; it < 4; ++it) {
    float4 v = src[it * 64 + lane];
    s += v.x * v.x + v.y * v.y + v.z * v.z + v.w * v.w;
    ushort4 b;
    b.x = f2bf(v.x); b.y = f2bf(v.y); b.z = f2bf(v.z); b.w = f2bf(v.w);
    dst[it * 64 + lane] = b;
  }
#pragma unroll
  for (int off = 32; off; off >>= 1) s += __shfl_down(s, off);
  if (lane == 0) {
    sq[row] = s;
    rn[row] = 1.0f / fmaxf(sqrtf(s), COS_EPS);
  }
}

// ---------------- fused gram (256x256 tile) + epilogue ----------------
// 8 waves (2Mx4N), per-wave 128x64. BK=32, 4-slot LDS ring, stage 3 ahead.
// Fragment-register double-buffer: each iter issues next tile's 12 ds_reads
// + 4 global_load_lds BEFORE the 32-MFMA cluster on the current reg set.
// One barrier + counted lgkmcnt(12) + counted vmcnt(4) per K-tile.
extern "C" __global__ void __launch_bounds__(512, 2) gram_kernel(
    const ushort* __restrict__ Fb, const float* __restrict__ sq,
    const float* __restrict__ rn, const int* __restrict__ y,
    float* __restrict__ partials) {
  __shared__ __align__(16) ushort As[4][8192];   // 4 slots x 16KB (256x32 bf16)
  __shared__ __align__(16) ushort Bs[4][8192];

  // XCD-aware remap (256 % 8 == 0 -> simple bijection)
  const int wg = (int)(blockIdx.x & 7) * 32 + (int)(blockIdx.x >> 3);
  const int bi = wg >> 4, bj = wg & 15;

  const int tid  = threadIdx.x;
  const int lane = tid & 63;
  const int wid  = tid >> 6;
  const int wr   = wid >> 2;     // 0..1 : 128-row half
  const int wc   = wid & 3;      // 0..3 : 64-col group
  const int fr   = lane & 15, fg = lane >> 4;

  // staging source (pre-permuted global address; LDS written linearly):
  // LDS 16B-slot s = tid holds global (row=(tid>>6)*16+(tid&15), chunk=(tid>>4)&3)
  const int grow = ((tid >> 6) << 4) + (tid & 15);
  const int gchk = ((tid >> 4) & 3) * 8;
  const ushort* gA = Fb + (size_t)(bi * 256 + grow) * DDIM + gchk;
  const ushort* gB = Fb + (size_t)(bj * 256 + grow) * DDIM + gchk;
  ushort* ldsA = &As[0][0] + tid * 8;
  ushort* ldsB = &Bs[0][0] + tid * 8;

  const int aoff = wr * 4096 + lane * 8;   // ushort units within a slot
  const int boff = wc * 2048 + lane * 8;

  f32x4 acc[8][4] = {};
  bf16x8 fa[2][8], fb[2][4];

#define STAGE(kt3) do {                                                     \
    const int _sl = (kt3) & 3;                                              \
    const ushort* _sa = gA + (kt3) * 32;                                    \
    const ushort* _sb = gB + (kt3) * 32;                                    \
    gload16(_sa, ldsA + _sl * 8192);                                        \
    gload16(_sa + (size_t)128 * DDIM, ldsA + _sl * 8192 + 4096);            \
    gload16(_sb, ldsB + _sl * 8192);                                        \
    gload16(_sb + (size_t)128 * DDIM, ldsB + _sl * 8192 + 4096);            \
  } while (0)

#define LOADFRAGS(set, kt1) do {                                            \
    const ushort* _ap = &As[(kt1) & 3][0] + aoff;                           \
    const ushort* _bp = &Bs[(kt1) & 3][0] + boff;                           \
    _Pragma("unroll")                                                       \
    for (int _m = 0; _m < 8; ++_m)                                          \
      fa[set][_m] = *(const bf16x8*)(_ap + _m * 512);                       \
    _Pragma("unroll")                                                       \
    for (int _n = 0; _n < 4; ++_n)                                          \
      fb[set][_n] = *(const bf16x8*)(_bp + _n * 512);                       \
  } while (0)

#define MFMA32(set) do {                                                    \
    __builtin_amdgcn_s_setprio(1);                                          \
    _Pragma("unroll")                                                       \
    for (int _m = 0; _m < 8; ++_m)                                          \
      _Pragma("unroll")                                                     \
      for (int _n = 0; _n < 4; ++_n)                                        \
        acc[_m][_n] = __builtin_amdgcn_mfma_f32_16x16x32_bf16(              \
            fa[set][_m], fb[set][_n], acc[_m][_n], 0, 0, 0);                \
    __builtin_amdgcn_s_setprio(0);                                          \
  } while (0)

  // prologue: tiles 0,1,2 in flight; wait tile 0; load its fragments
  STAGE(0); STAGE(1); STAGE(2);
  asm volatile("s_waitcnt vmcnt(8)" ::: "memory");
  asm volatile("s_barrier" ::: "memory");
  LOADFRAGS(0, 0);

#pragma unroll
  for (int kt = 0; kt < NKT - 1; ++kt) {
    LOADFRAGS((kt + 1) & 1, kt + 1);         // 12 ds_reads for next tile
    if (kt + 3 < NKT) STAGE(kt + 3);         // 4 gloads, 3 tiles ahead
    asm volatile("s_waitcnt lgkmcnt(12)" ::: "memory");  // prev set ready
    MFMA32(kt & 1);                          // 32 MFMA overlap new ds_reads
    if (kt < NKT - 3) asm volatile("s_waitcnt vmcnt(4)" ::: "memory");
    else              asm volatile("s_waitcnt vmcnt(0)" ::: "memory");
    asm volatile("s_barrier" ::: "memory");  // slot rotation safe
  }
  asm volatile("s_waitcnt lgkmcnt(0)" ::: "memory");
  MFMA32((NKT - 1) & 1);

#undef STAGE
#undef LOADFRAGS
#undef MFMA32

  // ---------- epilogue (full gram: every pair once) ----------
  const int gi0 = bi * 256 + wr * 128 + fg * 4;
  const int gj0 = bj * 256 + wc * 64 + fr;
  float sqc[4], rnc[4];
  int   yc[4];
#pragma unroll
  for (int n = 0; n < 4; ++n) {
    const int gj = gj0 + n * 16;
    sqc[n] = sq[gj]; rnc[n] = rn[gj]; yc[n] = y[gj];
  }
  float lsum = 0.f;
#pragma unroll
  for (int m = 0; m < 8; ++m) {
#pragma unroll
    for (int v = 0; v < 4; ++v) {
      const int gi = gi0 + m * 16 + v;
      const float sqi = sq[gi], rni = rn[gi];
      const int yi = y[gi];
#pragma unroll
      for (int n = 0; n < 4; ++n) {
        const float g  = acc[m][n][v];
        const float d2 = sqi + sqc[n] - 2.0f * g;
        const float dist = d2 > 0.f ? sqrtf(d2) : 0.f;
        const float sim  = g * rni * rnc[n];
        lsum += (yi == yc[n]) ? (dist - sim) : (sim - dist);
      }
    }
  }
#pragma unroll
  for (int off = 32; off; off >>= 1) lsum += __shfl_down(lsum, off);
  __shared__ float wsum[8];
  if (lane == 0) wsum[wid] = lsum;
  __syncthreads();
  if (tid == 0) {
    float t = 0.f;
#pragma unroll
    for (int i = 0; i < 8; ++i) t += wsum[i];
    partials[blockIdx.x] = t;
  }
}

// ---------------- deterministic final reduce ----------------
extern "C" __global__ void __launch_bounds__(256) reduce_kernel(
    const float* __restrict__ partials, float* __restrict__ out) {
  float s = 0.f;
  for (int i = threadIdx.x; i < GBLK; i += 256) s += partials[i];
#pragma unroll
  for (int off = 32; off; off >>= 1) s += __shfl_down(s, off);
  __shared__ float ws[4];
  if ((threadIdx.x & 63) == 0) ws[threadIdx.x >> 6] = s;
  __syncthreads();
  if (threadIdx.x == 0) out[0] = ws[0] + ws[1] + ws[2] + ws[3];
}

extern "C" void kernel_launch(void* const* d_in, const int* in_sizes, int n_in,
                              void* d_out, int out_size, void* d_ws, size_t ws_size,
                              hipStream_t stream) {
  const float* F = (const float*)d_in[0];
  const int*   y = (const int*)d_in[1];
  float* out = (float*)d_out;

  ushort* Fb = (ushort*)d_ws;                                 // 8 MB bf16
  float*  sq = (float*)((char*)d_ws + (size_t)NROWS * DDIM * 2);
  float*  rn = sq + NROWS;
  float*  partials = rn + NROWS;

  prep_kernel<<<NROWS / 4, 256, 0, stream>>>(F, Fb, sq, rn);
  gram_kernel<<<GBLK, 512, 0, stream>>>(Fb, sq, rn, y, partials);
  reduce_kernel<<<1, 256, 0, stream>>>(partials, out);
}